// Round 15
// baseline (209.934 us; speedup 1.0000x reference)
//
#include <hip/hip_runtime.h>
#include <hip/hip_bf16.h>

// CausalMultiheadSelfAttention — B=2, S=2048, D=1024, H=16, dk=64
// R15: GEMMs K-split (R12's attention trick): 512 threads = 4 quadrants x
// 2 K-halves, each half an independent dbuf pipeline (16 iters over K=512),
// partials reduced via LDS at the end -> 16 waves/CU (2x R14). fp32->bf16
// conversion still fused in staging (no cast kernel; 4 launches).
// Attention/rope byte-identical to R12/R14.

#define BATCH   2
#define SEQLEN  2048
#define DMODEL  1024
#define NHEADS  16
#define DK      64

typedef __attribute__((ext_vector_type(8))) short bf16x8;
typedef __attribute__((ext_vector_type(4))) short bf16x4;
typedef __attribute__((ext_vector_type(4))) float f32x4;

__device__ __forceinline__ float fast_exp2(float x) {
#if __has_builtin(__builtin_amdgcn_exp2f)
  return __builtin_amdgcn_exp2f(x);
#else
  return exp2f(x);
#endif
}

// 8-element chunk load, converting to bf16 if the source is fp32
__device__ __forceinline__ bf16x8 load_cvt(const __hip_bfloat16* p) {
  return *(const bf16x8*)p;
}
__device__ __forceinline__ bf16x8 load_cvt(const float* p) {
  float4 a = *(const float4*)p;
  float4 b = *(const float4*)(p + 4);
  __hip_bfloat16 t[8];
  t[0] = __float2bfloat16(a.x); t[1] = __float2bfloat16(a.y);
  t[2] = __float2bfloat16(a.z); t[3] = __float2bfloat16(a.w);
  t[4] = __float2bfloat16(b.x); t[5] = __float2bfloat16(b.y);
  t[6] = __float2bfloat16(b.z); t[7] = __float2bfloat16(b.w);
  return *(const bf16x8*)t;
}

// ---- K-split MFMA GEMM core: 128x128 tile, 8 waves = 4 quadrants x 2 K-halves
// Each half: 16-iter reg-staged LDS double buffer over its K/2 range.
// After the loop, kh=1 partials are added into kh=0's acc via LDS.
// Callers: waves with kh!=0 must return after this; epilogue is kh=0-only.
template <typename TA, typename TW>
__device__ __forceinline__ void gemm_core_ks(
    const TA* __restrict__ A, const TW* __restrict__ W,
    int bm, int bn, int K, f32x4 (&acc)[4][4]) {
  __shared__ __hip_bfloat16 As[2][2][128 * 32];   // [kh][buf], 32 KB
  __shared__ __hip_bfloat16 Ws[2][2][128 * 32];   // 32 KB
  const int tid  = threadIdx.x;
  const int wave = tid >> 6, lane = tid & 63;
  const int kh   = wave >> 2;          // K half: 0 or 1
  const int wq   = wave & 3;           // output quadrant
  const int col  = lane & 15, quad = lane >> 4;
  const int wm   = (wq & 1) * 64, wn = (wq >> 1) * 64;
  const int srow = wq * 32;
  const int l4   = lane >> 2, sl = lane & 3;
  const int kbase = kh * (K >> 1);

  bf16x8 ra[2], rw[2];
  auto stage_load = [&](int k0) {
#pragma unroll
    for (int c = 0; c < 2; ++c) {
      int r = srow + c * 16 + l4;
      int g = sl ^ (r & 3);
      ra[c] = load_cvt(A + (size_t)(bm + r) * K + kbase + k0 + g * 8);
      rw[c] = load_cvt(W + (size_t)(bn + r) * K + kbase + k0 + g * 8);
    }
  };
  auto stage_write = [&](int buf) {
#pragma unroll
    for (int c = 0; c < 2; ++c) {
      int r = srow + c * 16 + l4;
      *(bf16x8*)&As[kh][buf][r * 32 + sl * 8] = ra[c];
      *(bf16x8*)&Ws[kh][buf][r * 32 + sl * 8] = rw[c];
    }
  };

  const int NK = K >> 6;               // iters per half: (K/2)/32
  stage_load(0);
  stage_write(0);
  __syncthreads();

  for (int i = 0; i < NK; ++i) {
    const int buf = i & 1;
    const bool pre = (i + 1 < NK);
    if (pre) stage_load((i + 1) * 32);  // long-shadow global loads

    bf16x8 af[4], bfr[4];
#pragma unroll
    for (int mt = 0; mt < 4; ++mt) {
      int r = wm + mt * 16 + col;
      af[mt] = *(const bf16x8*)&As[kh][buf][r * 32 + ((quad ^ (r & 3)) * 8)];
    }
#pragma unroll
    for (int nt = 0; nt < 4; ++nt) {
      int r = wn + nt * 16 + col;
      bfr[nt] = *(const bf16x8*)&Ws[kh][buf][r * 32 + ((quad ^ (r & 3)) * 8)];
    }
#pragma unroll
    for (int mt = 0; mt < 4; ++mt)
#pragma unroll
      for (int nt = 0; nt < 4; ++nt)
        acc[mt][nt] = __builtin_amdgcn_mfma_f32_16x16x32_bf16(af[mt], bfr[nt], acc[mt][nt], 0, 0, 0);

    if (pre) stage_write(buf ^ 1);      // vmcnt wait lands post-shadow
    __syncthreads();
  }

  // ---- cross-half reduction: kh=1 partials -> LDS -> kh=0 adds ----
  // Regions: wq 0,1 use As (8192 floats), wq 2,3 use Ws; 4096 floats each.
  float* red = (wq < 2) ? (float*)&As[0][0][0] : (float*)&Ws[0][0][0];
  float* reg = red + (wq & 1) * 4096;
  if (kh == 1) {
#pragma unroll
    for (int mt = 0; mt < 4; ++mt)
#pragma unroll
      for (int nt = 0; nt < 4; ++nt)
        *(f32x4*)(reg + ((mt * 4 + nt) * 64 + lane) * 4) = acc[mt][nt];
  }
  __syncthreads();
  if (kh == 0) {
#pragma unroll
    for (int mt = 0; mt < 4; ++mt)
#pragma unroll
      for (int nt = 0; nt < 4; ++nt)
        acc[mt][nt] += *(const f32x4*)(reg + ((mt * 4 + nt) * 64 + lane) * 4);
  }
}

// ---------------- fused QKV GEMM (z: 0=Q, 1=K, 2=V-transposed) ---------------
__global__ __launch_bounds__(512) void mfma_qkv(
    const float* __restrict__ x,
    const float* __restrict__ wq,
    const float* __restrict__ wk,
    const float* __restrict__ wv,
    __hip_bfloat16* __restrict__ Qw,
    __hip_bfloat16* __restrict__ Kw,
    __hip_bfloat16* __restrict__ Vtw) {
  const int z = blockIdx.z;
  const float* W = (z == 0) ? wq : (z == 1) ? wk : wv;
  const int bm = blockIdx.x * 128, bn = blockIdx.y * 128;
  f32x4 acc[4][4] = {};
  gemm_core_ks(x, W, bm, bn, DMODEL, acc);
  if (threadIdx.x >= 256) return;      // kh=1 waves done

  const int wave = threadIdx.x >> 6, lane = threadIdx.x & 63;
  const int col  = lane & 15, quad = lane >> 4;
  const int wm   = (wave & 1) * 64, wn = (wave >> 1) * 64;

  if (z < 2) {
    __hip_bfloat16* C = (z == 0) ? Qw : Kw;
#pragma unroll
    for (int mt = 0; mt < 4; ++mt)
#pragma unroll
      for (int nt = 0; nt < 4; ++nt) {
        int n = bn + wn + nt * 16 + col;
#pragma unroll
        for (int r = 0; r < 4; ++r) {
          int m = bm + wm + mt * 16 + quad * 4 + r;
          C[(size_t)m * DMODEL + n] = __float2bfloat16(acc[mt][nt][r]);
        }
      }
  } else {
#pragma unroll
    for (int mt = 0; mt < 4; ++mt)
#pragma unroll
      for (int nt = 0; nt < 4; ++nt) {
        int n  = bn + wn + nt * 16 + col;          // h = n>>6, dk = n&63
        int m0 = bm + wm + mt * 16 + quad * 4;     // b = m0>>11, s = m0&2047
        __hip_bfloat16 t[4];
#pragma unroll
        for (int r = 0; r < 4; ++r) t[r] = __float2bfloat16(acc[mt][nt][r]);
        size_t off = (((size_t)(m0 >> 11) * NHEADS + (n >> 6)) * DK + (n & 63)) * SEQLEN + (m0 & 2047);
        *(bf16x4*)(Vtw + off) = *(const bf16x4*)t;
      }
  }
}

// ---------------- out-projection GEMM: bf16 A x fp32 W -> fp32 out -----------
__global__ __launch_bounds__(512) void mfma_out(
    const __hip_bfloat16* __restrict__ Ow,
    const float* __restrict__ wo,
    float* __restrict__ out) {
  const int bm = blockIdx.x * 128, bn = blockIdx.y * 128;
  f32x4 acc[4][4] = {};
  gemm_core_ks(Ow, wo, bm, bn, DMODEL, acc);
  if (threadIdx.x >= 256) return;      // kh=1 waves done

  const int wave = threadIdx.x >> 6, lane = threadIdx.x & 63;
  const int col  = lane & 15, quad = lane >> 4;
  const int wm   = (wave & 1) * 64, wn = (wave >> 1) * 64;
#pragma unroll
  for (int mt = 0; mt < 4; ++mt)
#pragma unroll
    for (int nt = 0; nt < 4; ++nt) {
      int n = bn + wn + nt * 16 + col;
#pragma unroll
      for (int r = 0; r < 4; ++r) {
        int m = bm + wm + mt * 16 + quad * 4 + r;
        out[(size_t)m * DMODEL + n] = acc[mt][nt][r];
      }
    }
}

// ---------------- RoPE; Q additionally scaled by 0.125*log2(e) ---------------
__global__ __launch_bounds__(256) void rope_kernel(
    __hip_bfloat16* __restrict__ Q,
    __hip_bfloat16* __restrict__ Kt,
    const int* __restrict__ pos, int npairs) {
  int idx = blockIdx.x * blockDim.x + threadIdx.x;
  if (idx >= npairs) return;
  int ip = idx & 511;
  int s  = (idx >> 9) & (SEQLEN - 1);
  int p  = ip & 31;
  float inv_freq = exp2f(-13.287712379549449f * ((float)(2 * p) / 64.0f));
  float ang = (float)pos[s] * inv_freq;
  float sn, cs;
  sincosf(ang, &sn, &cs);
  const float SCL = 0.18033688011112042f;  // 0.125 * log2(e)
  size_t off = (size_t)idx * 2;
  float qe = __bfloat162float(Q[off]), qo = __bfloat162float(Q[off + 1]);
  Q[off]     = __float2bfloat16((qe * cs - qo * sn) * SCL);
  Q[off + 1] = __float2bfloat16((qo * cs + qe * sn) * SCL);
  float ke = __bfloat162float(Kt[off]), ko = __bfloat162float(Kt[off + 1]);
  Kt[off]     = __float2bfloat16(ke * cs - ko * sn);
  Kt[off + 1] = __float2bfloat16(ko * cs + ke * sn);
}

// ---------------- K-split staged MFMA flash attention (R12) ------------------
__global__ __launch_bounds__(512) void attn_mfma(
    const __hip_bfloat16* __restrict__ Q,
    const __hip_bfloat16* __restrict__ K,
    const __hip_bfloat16* __restrict__ Vt,
    __hip_bfloat16* __restrict__ O) {
  __shared__ __align__(16) __hip_bfloat16 Ks[2][64 * 64];   // 16 KB
  __shared__ __align__(16) __hip_bfloat16 Vs[2][64 * 64];   // 16 KB
  __shared__ __align__(16) __hip_bfloat16 Pl[8][32 * 64];   // 32 KB (+fp32 scratch)
  const int lin  = (int)blockIdx.y * (int)gridDim.x + (int)blockIdx.x;  // 0..511
  const int xcd  = lin & 7, slot = lin >> 3;
  const int bh   = xcd * 4 + (slot & 3);
  const int strip = 15 - (slot >> 2);       // heavy blocks dispatched first
  const int b = bh >> 4, h = bh & 15;
  const int wave = threadIdx.x >> 6;        // 0..7
  const int lane = threadIdx.x & 63;
  const int qg = wave & 3;                  // query group: 32 q each
  const int kg = wave >> 2;                 // key half: even/odd 64-tile
  const int col = lane & 15, quad = lane >> 4;
  const int q0w = strip * 128 + qg * 32;    // wave's first query
  const int cswz = col & 7;

  const size_t qkbase = ((size_t)b * SEQLEN) * DMODEL + (size_t)h * DK;
  const size_t vbase  = (size_t)bh * DK * SEQLEN;
  __hip_bfloat16* pl = &Pl[wave][0];

  const int sr = ((int)threadIdx.x >> 3) & 63;
  const int sl = (int)threadIdx.x & 7;
  const int sgch = sl ^ (sr & 7);           // swizzled global 16B chunk

  bf16x8 stK[2], stV[2];
  auto stage_load = [&](int p) {
    const int j0 = p * 128;
#pragma unroll
    for (int g = 0; g < 2; ++g) {
      stK[g] = *(const bf16x8*)(K + qkbase + (size_t)(j0 + g * 64 + sr) * DMODEL + sgch * 8);
      stV[g] = *(const bf16x8*)(Vt + vbase + (size_t)sr * SEQLEN + j0 + g * 64 + sgch * 8);
    }
  };
  auto stage_write = [&]() {
#pragma unroll
    for (int g = 0; g < 2; ++g) {
      *(bf16x8*)&Ks[g][sr * 64 + sl * 8] = stK[g];
      *(bf16x8*)&Vs[g][sr * 64 + sl * 8] = stV[g];
    }
  };

  bf16x8 qf[2][2];
#pragma unroll
  for (int qt = 0; qt < 2; ++qt)
#pragma unroll
    for (int kc = 0; kc < 2; ++kc)
      qf[qt][kc] = *(const bf16x8*)(Q + qkbase +
          (size_t)(q0w + qt * 16 + col) * DMODEL + kc * 32 + quad * 8);

  f32x4 acc[2][4] = {};            // O^T partial (this wave's key half)
  float l_i[2] = {0.f, 0.f};       // partial softmax denominators

  const bool skip_last = (kg == 1) && (qg < 2);  // fully-masked final tile

  stage_load(0);
  stage_write();
  __syncthreads();

  for (int p = 0; p <= strip; ++p) {
    const bool pre  = p < strip;
    const bool last = p == strip;
    if (pre) stage_load(p + 1);          // long-shadow global loads

    if (!(last && skip_last)) {
      const int kb = p * 128 + kg * 64;  // this wave's key base

      f32x4 s[2][4] = {};
#pragma unroll
      for (int kt = 0; kt < 4; ++kt) {
        const int row = kt * 16 + col;
#pragma unroll
        for (int kc = 0; kc < 2; ++kc) {
          bf16x8 kf = *(const bf16x8*)&Ks[kg][row * 64 + (((kc * 4 + quad) ^ cswz) * 8)];
#pragma unroll
          for (int qt = 0; qt < 2; ++qt)
            s[qt][kt] = __builtin_amdgcn_mfma_f32_16x16x32_bf16(kf, qf[qt][kc], s[qt][kt], 0, 0, 0);
        }
      }

      if (last) {
#pragma unroll
        for (int qt = 0; qt < 2; ++qt) {
          const int q = q0w + qt * 16 + col;
#pragma unroll
          for (int kt = 0; kt < 4; ++kt)
#pragma unroll
            for (int r = 0; r < 4; ++r)
              if (kb + kt * 16 + quad * 4 + r > q) s[qt][kt][r] = -1e30f;
        }
      }

#pragma unroll
      for (int qt = 0; qt < 2; ++qt) {
#pragma unroll
        for (int kt = 0; kt < 4; ++kt) {
          __hip_bfloat16 tp[4];
#pragma unroll
          for (int r = 0; r < 4; ++r) {
            float pv = fast_exp2(s[qt][kt][r] - 24.0f);
            l_i[qt] += pv;
            tp[r] = __float2bfloat16(pv);
          }
          int c2 = ((kt << 1) | (quad >> 1)) ^ cswz;
          *(bf16x4*)(pl + (qt * 16 + col) * 64 + c2 * 8 + (quad & 1) * 4) = *(const bf16x4*)tp;
        }
      }

#pragma unroll
      for (int jc = 0; jc < 2; ++jc) {
        const int c2 = ((jc << 2) | quad) ^ cswz;
        bf16x8 pf[2];
#pragma unroll
        for (int qt = 0; qt < 2; ++qt)
          pf[qt] = *(const bf16x8*)(pl + (qt * 16 + col) * 64 + c2 * 8);
#pragma unroll
        for (int dt = 0; dt < 4; ++dt) {
          const int dv = dt * 16 + col;
          bf16x8 vf = *(const bf16x8*)&Vs[kg][dv * 64 + (((jc * 4 + quad) ^ cswz) * 8)];
#pragma unroll
          for (int qt = 0; qt < 2; ++qt)
            acc[qt][dt] = __builtin_amdgcn_mfma_f32_16x16x32_bf16(vf, pf[qt], acc[qt][dt], 0, 0, 0);
        }
      }
    }

    __syncthreads();                 // all waves done reading this pair
    if (pre) { stage_write(); __syncthreads(); }
  }

  // ---- cross-kg reduction (Pl reused as fp32 scratch), then epilogue ----
  float* accbuf = (float*)&Pl[0][0];
  float* lbuf   = (float*)&Ks[0][0];
  if (kg == 1) {
#pragma unroll
    for (int qt = 0; qt < 2; ++qt)
#pragma unroll
      for (int dt = 0; dt < 4; ++dt)
        *(f32x4*)(accbuf + ((qg * 8 + qt * 4 + dt) * 64 + lane) * 4) = acc[qt][dt];
    lbuf[(qg * 64 + lane) * 2 + 0] = l_i[0];
    lbuf[(qg * 64 + lane) * 2 + 1] = l_i[1];
  }
  __syncthreads();
  if (kg == 0) {
#pragma unroll
    for (int qt = 0; qt < 2; ++qt)
#pragma unroll
      for (int dt = 0; dt < 4; ++dt) {
        f32x4 o = *(const f32x4*)(accbuf + ((qg * 8 + qt * 4 + dt) * 64 + lane) * 4);
        acc[qt][dt] += o;
      }
    l_i[0] += lbuf[(qg * 64 + lane) * 2 + 0];
    l_i[1] += lbuf[(qg * 64 + lane) * 2 + 1];

#pragma unroll
    for (int qt = 0; qt < 2; ++qt) {
      float l = l_i[qt];
      l += __shfl_xor(l, 16, 64);
      l += __shfl_xor(l, 32, 64);
      const float inv = 1.f / l;
      const size_t orow = qkbase + (size_t)(q0w + qt * 16 + col) * DMODEL;
#pragma unroll
      for (int dt = 0; dt < 4; ++dt) {
        __hip_bfloat16 tp[4];
#pragma unroll
        for (int r = 0; r < 4; ++r) tp[r] = __float2bfloat16(acc[qt][dt][r] * inv);
        *(bf16x4*)(O + orow + dt * 16 + quad * 4) = *(const bf16x4*)tp;
      }
    }
  }
}

// ---------------- launch -----------------------------------------------------
extern "C" void kernel_launch(void* const* d_in, const int* in_sizes, int n_in,
                              void* d_out, int out_size, void* d_ws, size_t ws_size,
                              hipStream_t stream) {
  const float* x  = (const float*)d_in[0];
  const float* Wq = (const float*)d_in[1];
  const float* Wk = (const float*)d_in[2];
  const float* Wv = (const float*)d_in[3];
  const float* Wo = (const float*)d_in[4];
  const int* pos  = (const int*)d_in[5];
  float* out = (float*)d_out;

  const size_t NELEM = (size_t)BATCH * SEQLEN * DMODEL;  // 4 Mi
  __hip_bfloat16* Qw  = (__hip_bfloat16*)d_ws;
  __hip_bfloat16* Kw  = Qw + NELEM;
  __hip_bfloat16* Vtw = Kw + NELEM;                      // [b][h][dk][s]
  __hip_bfloat16* Ow  = Vtw + NELEM;

  mfma_qkv<<<dim3(32, 8, 3), 512, 0, stream>>>(x, Wq, Wk, Wv, Qw, Kw, Vtw);

  int npairs = BATCH * SEQLEN * (DMODEL / 2);
  rope_kernel<<<(npairs + 255) / 256, 256, 0, stream>>>(Qw, Kw, pos, npairs);

  attn_mfma<<<dim3(16, BATCH * NHEADS), 512, 0, stream>>>(Qw, Kw, Vtw, Ow);

  mfma_out<<<dim3(32, 8), 512, 0, stream>>>(Ow, Wo, out);
}